// Round 1
// 1085.512 us; speedup vs baseline: 2.9243x; 2.9243x over previous
//
#include <hip/hip_runtime.h>
#include <hip/hip_bf16.h>

#define DIM 384
#define NHEADS 12
#define NTOK 49
#define NWIN 4096
#define MTOT (NWIN * NTOK)   /* 200704 */
#define QKVN (3 * DIM)       /* 1152 */
#define QSCALE 0.17677669529663687f

using f32x4  = __attribute__((ext_vector_type(4))) float;
using bf16x8 = __attribute__((ext_vector_type(8))) short;

__device__ __forceinline__ unsigned short f2bf(float f) {
  __hip_bfloat16 h = __float2bfloat16(f);
  return __builtin_bit_cast(unsigned short, h);
}
__device__ __forceinline__ float bf2f(unsigned short u) {
  unsigned int v = ((unsigned int)u) << 16;
  return __builtin_bit_cast(float, v);
}

__device__ __forceinline__ void async_ld16(const void* g, void* l) {
  __builtin_amdgcn_global_load_lds(
      (const __attribute__((address_space(1))) void*)g,
      (__attribute__((address_space(3))) void*)l, 16, 0, 0);
}

// ---------------- prep kernels ----------------
__global__ void cvt_x_kernel(const float* __restrict__ X, unsigned short* __restrict__ Y, int n4) {
  int i = blockIdx.x * 256 + threadIdx.x;
  if (i >= n4) return;
  const float4 xv = ((const float4*)X)[i];
  ushort4 o;
  o.x = f2bf(xv.x); o.y = f2bf(xv.y); o.z = f2bf(xv.z); o.w = f2bf(xv.w);
  ((ushort4*)Y)[i] = o;
}

// W[K][N] (row-major) -> Wt[N][K] bf16
__global__ void transp_w_kernel(const float* __restrict__ W, unsigned short* __restrict__ Wt,
                                int K, int N) {
  int idx = blockIdx.x * 256 + threadIdx.x;
  if (idx >= K * N) return;
  int n = idx / K, kk = idx % K;
  Wt[idx] = f2bf(W[kk * N + n]);
}

// Expand relative-position bias into the MFMA C-operand (D-layout) per head.
// Layout: bias_dl[((h*16 + r*4 + c)*64 + lane)*4 + i] = Bpad(h, qi=16c+(lane&15),
//          kj=16r+4*(lane>>4)+i);  kj>=49 -> -1e30 (masks padded keys), qi>=49 -> 0.
__global__ void bias_prep_kernel(const float* __restrict__ bias_table,
                                 const int* __restrict__ rel_idx,
                                 float* __restrict__ bias_dl) {
  int idx = blockIdx.x * 256 + threadIdx.x;   // 12*16*64*4 = 49152
  if (idx >= NHEADS * 16 * 64 * 4) return;
  int i = idx & 3, lane = (idx >> 2) & 63, rc = (idx >> 8) & 15, h = idx >> 12;
  int r = rc >> 2, c = rc & 3;
  int qi = 16 * c + (lane & 15);
  int kj = 16 * r + 4 * (lane >> 4) + i;
  float v;
  if (kj >= NTOK)      v = -1e30f;
  else if (qi >= NTOK) v = 0.0f;
  else                 v = bias_table[rel_idx[qi * NTOK + kj] * NHEADS + h];
  bias_dl[idx] = v;
}

// ---------------- GEMM: C[M,N] = A[M,K] * Bt[N,K]^T (+bias, opt q-scale) ----------------
template <int N, int K, bool OUT_BF16, bool SCALE_Q>
__global__ __launch_bounds__(256)
void gemm_bt(const unsigned short* __restrict__ A,
             const unsigned short* __restrict__ Bt,
             void* __restrict__ Cv,
             const float* __restrict__ bias) {
  __shared__ __align__(16) unsigned short As[128 * 32];
  __shared__ __align__(16) unsigned short Bs[128 * 32];
  const int t    = threadIdx.x;
  const int wave = t >> 6;
  const int lane = t & 63;
  const int fr   = lane & 15;
  const int quad = lane >> 4;
  const int wr   = (wave >> 1) * 64;   // wave's row quadrant
  const int wc   = (wave & 1) * 64;    // wave's col quadrant
  const size_t m0 = (size_t)blockIdx.x * 128;
  const int    n0 = blockIdx.y * 128;

  f32x4 acc[4][4] = {};

  // staging: 512 chunks of 16B per tile; chunk = (wave*2+i)*64 + lane
  const int c0 = (wave * 2 + 0) * 64 + lane;
  const int c1 = (wave * 2 + 1) * 64 + lane;
  const unsigned short* ga0 = A + (m0 + (size_t)(c0 >> 2)) * K + (c0 & 3) * 8;
  const unsigned short* ga1 = A + (m0 + (size_t)(c1 >> 2)) * K + (c1 & 3) * 8;
  const unsigned short* gb0 = Bt + (size_t)(n0 + (c0 >> 2)) * K + (c0 & 3) * 8;
  const unsigned short* gb1 = Bt + (size_t)(n0 + (c1 >> 2)) * K + (c1 & 3) * 8;
  unsigned short* la0 = As + (wave * 2 + 0) * 64 * 8;
  unsigned short* la1 = As + (wave * 2 + 1) * 64 * 8;
  unsigned short* lb0 = Bs + (wave * 2 + 0) * 64 * 8;
  unsigned short* lb1 = Bs + (wave * 2 + 1) * 64 * 8;

  for (int kt = 0; kt < K; kt += 32) {
    async_ld16(ga0 + kt, la0);
    async_ld16(ga1 + kt, la1);
    async_ld16(gb0 + kt, lb0);
    async_ld16(gb1 + kt, lb1);
    __syncthreads();
    bf16x8 af[4], bfr[4];
#pragma unroll
    for (int r = 0; r < 4; ++r)
      af[r] = *(const bf16x8*)&As[(wr + r * 16 + fr) * 32 + quad * 8];
#pragma unroll
    for (int c = 0; c < 4; ++c)
      bfr[c] = *(const bf16x8*)&Bs[(wc + c * 16 + fr) * 32 + quad * 8];
#pragma unroll
    for (int r = 0; r < 4; ++r)
#pragma unroll
      for (int c = 0; c < 4; ++c)
        acc[r][c] = __builtin_amdgcn_mfma_f32_16x16x32_bf16(af[r], bfr[c], acc[r][c], 0, 0, 0);
    __syncthreads();
  }

  // epilogue: D layout col=lane&15, row=(lane>>4)*4+reg
#pragma unroll
  for (int r = 0; r < 4; ++r) {
#pragma unroll
    for (int i = 0; i < 4; ++i) {
      size_t m = m0 + wr + r * 16 + quad * 4 + i;
#pragma unroll
      for (int c = 0; c < 4; ++c) {
        int n = n0 + wc + c * 16 + fr;
        float v = acc[r][c][i] + bias[n];
        if (SCALE_Q && n < DIM) v *= QSCALE;
        if (OUT_BF16)
          ((unsigned short*)Cv)[m * N + n] = f2bf(v);
        else
          ((float*)Cv)[m * N + n] = v;
      }
    }
  }
}

// ---------------- attention: one WAVE per (window, head), MFMA ----------------
// S^T = mfma(A=K, B=Q) so softmax's k-axis is (regs + quad) local: 2 shfl_xor only.
// P is stored to LDS as bf16 hi+lo split (error ~2^-17) for the PV MFMAs.
// Bias (with -1e30 key-padding mask baked in) arrives pre-swizzled into the
// accumulator's D-layout and is used as the MFMA C operand directly.
__global__ __launch_bounds__(256)
void attn_kernel(const unsigned short* __restrict__ qkv,
                 const float* __restrict__ bias_dl,
                 unsigned short* __restrict__ ao) {
  // per-wave private LDS regions -> no __syncthreads needed anywhere
  __shared__ unsigned short Ps[4][128][64];  // rows 0..63 = P_hi[q][k], 64..127 = P_lo
  __shared__ unsigned short Vt[4][32][64];   // Vt[d][token]
  const int t  = threadIdx.x;
  const int wv = t >> 6, lane = t & 63;
  const int f  = lane & 15, qd = lane >> 4;
  const int b  = blockIdx.x;
  const int h  = blockIdx.y * 4 + wv;
  const unsigned short* base = qkv + (size_t)b * NTOK * QKVN + h * 32;

  // read-side chunk swizzle (rows accessed as 16rt+f): depends only on f
  const int xfl = (f & 7) ^ ((f >> 3) & 1);

  // ---- global fragment loads (each instr = 16 fully-consumed 64B lines) ----
  bf16x8 kf[4], qf[4], vf[4];
#pragma unroll
  for (int r = 0; r < 4; ++r) {
    int row = f + 16 * r; if (row > NTOK - 1) row = NTOK - 1;   // clamp: finite dup data
    const unsigned short* rp = base + (size_t)row * QKVN + qd * 8;
    qf[r] = *(const bf16x8*)(rp);
    kf[r] = *(const bf16x8*)(rp + DIM);
    vf[r] = *(const bf16x8*)(rp + 2 * DIM);
  }

  // ---- bias as initial accumulator (C operand), coalesced f32x4 ----
  f32x4 acc[4][4];
#pragma unroll
  for (int r = 0; r < 4; ++r)
#pragma unroll
    for (int c = 0; c < 4; ++c)
      acc[r][c] = *(const f32x4*)&bias_dl[(((h * 16 + r * 4 + c) << 6) + lane) << 2];

  // ---- V transpose into LDS: lane holds V[tok=f+16r][d=8qd+j] -> Vt[d][tok] ----
#pragma unroll
  for (int r = 0; r < 4; ++r) {
    const int col = f + 16 * r;                  // unclamped token col (inits all 64)
#pragma unroll
    for (int j = 0; j < 8; ++j) {
      const int d   = 8 * qd + j;
      const int xfv = (d & 7) ^ ((d >> 3) & 1);  // = j ^ (qd&1)
      const int cs  = (col & 7) | (((col >> 3) ^ xfv) << 3);
      Vt[wv][d][cs] = (unsigned short)vf[r][j];
    }
  }

  // ---- S^T: 16 MFMA, k = full head_dim 32 in one shot ----
#pragma unroll
  for (int r = 0; r < 4; ++r)
#pragma unroll
    for (int c = 0; c < 4; ++c)
      acc[r][c] = __builtin_amdgcn_mfma_f32_16x16x32_bf16(kf[r], qf[c], acc[r][c], 0, 0, 0);

  // ---- softmax over k (rows of S^T): in-lane over (r,i) + shfl over quads ----
  // masked keys carry -1e30 bias -> exp underflows to exactly 0, no branches.
#pragma unroll
  for (int c = 0; c < 4; ++c) {
    float mx = acc[0][c][0];
#pragma unroll
    for (int r = 0; r < 4; ++r)
#pragma unroll
      for (int i = 0; i < 4; ++i) mx = fmaxf(mx, acc[r][c][i]);
    mx = fmaxf(mx, __shfl_xor(mx, 16));
    mx = fmaxf(mx, __shfl_xor(mx, 32));
    float sum = 0.f;
#pragma unroll
    for (int r = 0; r < 4; ++r)
#pragma unroll
      for (int i = 0; i < 4; ++i) {
        float p = __expf(acc[r][c][i] - mx);
        acc[r][c][i] = p;
        sum += p;
      }
    sum += __shfl_xor(sum, 16);
    sum += __shfl_xor(sum, 32);
    const float inv = 1.0f / sum;
#pragma unroll
    for (int r = 0; r < 4; ++r)
#pragma unroll
      for (int i = 0; i < 4; ++i) acc[r][c][i] *= inv;
  }

  // ---- P -> bf16 hi/lo, packed 4-wide b64 stores into swizzled Ps ----
  // lane's (r,c) quad holds 4 CONSECUTIVE k-cols (16r+4qd+i) of q-row 16c+f.
#pragma unroll
  for (int c = 0; c < 4; ++c) {
    const int row = 16 * c + f;
#pragma unroll
    for (int r = 0; r < 4; ++r) {
      const int chunk = (2 * r + (qd >> 1)) ^ xfl;
      const int off   = chunk * 8 + 4 * (qd & 1);
      unsigned int u0 = __builtin_bit_cast(unsigned int, acc[r][c][0]);
      unsigned int u1 = __builtin_bit_cast(unsigned int, acc[r][c][1]);
      unsigned int u2 = __builtin_bit_cast(unsigned int, acc[r][c][2]);
      unsigned int u3 = __builtin_bit_cast(unsigned int, acc[r][c][3]);
      uint2 hi2;
      hi2.x = (u0 >> 16) | (u1 & 0xFFFF0000u);
      hi2.y = (u2 >> 16) | (u3 & 0xFFFF0000u);
      float l0 = acc[r][c][0] - __builtin_bit_cast(float, u0 & 0xFFFF0000u);
      float l1 = acc[r][c][1] - __builtin_bit_cast(float, u1 & 0xFFFF0000u);
      float l2 = acc[r][c][2] - __builtin_bit_cast(float, u2 & 0xFFFF0000u);
      float l3 = acc[r][c][3] - __builtin_bit_cast(float, u3 & 0xFFFF0000u);
      uint2 lo2;
      lo2.x = (__builtin_bit_cast(unsigned int, l0) >> 16) |
              (__builtin_bit_cast(unsigned int, l1) & 0xFFFF0000u);
      lo2.y = (__builtin_bit_cast(unsigned int, l2) >> 16) |
              (__builtin_bit_cast(unsigned int, l3) & 0xFFFF0000u);
      *(uint2*)&Ps[wv][row][off]      = hi2;
      *(uint2*)&Ps[wv][64 + row][off] = lo2;
    }
  }

  // all LDS writes (Vt + Ps) drained before PV fragment reads; DS is in-order
  // per wave, the asm pins compiler ordering across the write->read boundary.
  asm volatile("s_waitcnt lgkmcnt(0)" ::: "memory");

  // ---- O = (P_hi + P_lo) V : 32 MFMA ----
  f32x4 oacc[4][2] = {};
#pragma unroll
  for (int kb = 0; kb < 2; ++kb) {
    bf16x8 bv[2];
#pragma unroll
    for (int ct = 0; ct < 2; ++ct) {
      const int chunk = ((4 * kb + qd) ^ xfl);
      bv[ct] = *(const bf16x8*)&Vt[wv][16 * ct + f][chunk * 8];
    }
#pragma unroll
    for (int rt = 0; rt < 4; ++rt) {
      const int chunk = ((4 * kb + qd) ^ xfl);
      const bf16x8 phi = *(const bf16x8*)&Ps[wv][16 * rt + f][chunk * 8];
      const bf16x8 plo = *(const bf16x8*)&Ps[wv][64 + 16 * rt + f][chunk * 8];
#pragma unroll
      for (int ct = 0; ct < 2; ++ct) {
        oacc[rt][ct] = __builtin_amdgcn_mfma_f32_16x16x32_bf16(phi, bv[ct], oacc[rt][ct], 0, 0, 0);
        oacc[rt][ct] = __builtin_amdgcn_mfma_f32_16x16x32_bf16(plo, bv[ct], oacc[rt][ct], 0, 0, 0);
      }
    }
  }

  // ---- store O (D-layout: row = 16rt+4qd+i, col d = 16ct+f) ----
  unsigned short* ob = ao + (size_t)b * NTOK * DIM + h * 32;
#pragma unroll
  for (int rt = 0; rt < 4; ++rt)
#pragma unroll
    for (int i = 0; i < 4; ++i) {
      const int qi = 16 * rt + 4 * qd + i;
      if (qi < NTOK) {
#pragma unroll
        for (int ct = 0; ct < 2; ++ct)
          ob[(size_t)qi * DIM + 16 * ct + f] = f2bf(oacc[rt][ct][i]);
      }
    }
}

// ---------------- launch ----------------
extern "C" void kernel_launch(void* const* d_in, const int* in_sizes, int n_in,
                              void* d_out, int out_size, void* d_ws, size_t ws_size,
                              hipStream_t stream) {
  const float* x          = (const float*)d_in[0];
  const float* qkv_w      = (const float*)d_in[1];
  const float* qkv_b      = (const float*)d_in[2];
  const float* proj_w     = (const float*)d_in[3];
  const float* proj_b     = (const float*)d_in[4];
  const float* bias_table = (const float*)d_in[5];
  const int*   rel_idx    = (const int*)d_in[6];

  char* ws = (char*)d_ws;
  const size_t SZ_XBF  = (size_t)MTOT * DIM * 2;   // 154,140,672
  const size_t SZ_W1T  = (size_t)QKVN * DIM * 2;   // 884,736
  const size_t SZ_W2T  = (size_t)DIM * DIM * 2;    // 294,912
  const size_t SZ_QKV  = (size_t)MTOT * QKVN * 2;  // 462,422,016
  unsigned short* x_bf = (unsigned short*)(ws);
  unsigned short* w1t  = (unsigned short*)(ws + SZ_XBF);
  unsigned short* w2t  = (unsigned short*)(ws + SZ_XBF + SZ_W1T);
  unsigned short* qkv  = (unsigned short*)(ws + SZ_XBF + SZ_W1T + SZ_W2T);
  unsigned short* ao   = (unsigned short*)(ws + SZ_XBF + SZ_W1T + SZ_W2T + SZ_QKV);
  // bias_dl (196,608 B) lives in d_out: only needed before gemm2 overwrites it.
  float* bias_dl = (float*)d_out;

  const int n4 = MTOT * DIM / 4;  // 19,267,584
  hipLaunchKernelGGL(cvt_x_kernel, dim3((n4 + 255) / 256), dim3(256), 0, stream, x, x_bf, n4);
  hipLaunchKernelGGL(transp_w_kernel, dim3((DIM * QKVN + 255) / 256), dim3(256), 0, stream,
                     qkv_w, w1t, DIM, QKVN);
  hipLaunchKernelGGL(transp_w_kernel, dim3((DIM * DIM + 255) / 256), dim3(256), 0, stream,
                     proj_w, w2t, DIM, DIM);
  hipLaunchKernelGGL(bias_prep_kernel, dim3(192), dim3(256), 0, stream,
                     bias_table, rel_idx, bias_dl);
  hipLaunchKernelGGL((gemm_bt<QKVN, DIM, true, true>), dim3(MTOT / 128, QKVN / 128), dim3(256),
                     0, stream, x_bf, w1t, (void*)qkv, qkv_b);
  hipLaunchKernelGGL(attn_kernel, dim3(NWIN, NHEADS / 4), dim3(256), 0, stream,
                     qkv, bias_dl, ao);
  hipLaunchKernelGGL((gemm_bt<DIM, DIM, false, false>), dim3(MTOT / 128, DIM / 128), dim3(256),
                     0, stream, ao, w2t, d_out, proj_b);
}